// Round 7
// baseline (472.186 us; speedup 1.0000x reference)
//
#include <hip/hip_runtime.h>
#include <hip/hip_bf16.h>

// GAE forward, bf16 compute path + fp8 message tensor.
//   CSR build: count -> 3-phase scan -> BINNED 2-phase scatter
//     (bucket = dst>>6; bucket col regions are rowptr slices, so offsets are free)
//   -> cvt x->bf16, pack weights to MFMA frag order
//   -> 5x bf16-MFMA GEMM (encoder x2 -> bf16 out; conv x3 -> fp8(x32)*dinv out)
//   -> 3x mp gather (fp8 rows, x4-unrolled, f32 accum, bf16 h out)
//   -> grid-strided pool -> head (f32) -> fill(sigmoid const)
// edge_probs is constant: node_emb rows are the same broadcast vector v,
// so logit = sum(v*v) for every edge.

typedef __attribute__((ext_vector_type(8))) short bf16x8;
typedef __attribute__((ext_vector_type(4))) float f32x4;
typedef __attribute__((ext_vector_type(2))) float f32x2;

#define FP8_SCALE 32.0f
#define FP8_INV (1.0f / 32.0f)

__device__ __forceinline__ ushort f2bf(float f) {
  union { float f; unsigned u; } v; v.f = f;
  unsigned r = v.u + 0x7FFF + ((v.u >> 16) & 1);  // RNE
  return (ushort)(r >> 16);
}
__device__ __forceinline__ float bf2f(ushort b) {
  union { unsigned u; float f; } v; v.u = ((unsigned)b) << 16;
  return v.f;
}

// -------------------- CSR build --------------------

__global__ void detect_i64_kernel(const int* __restrict__ ei, int* __restrict__ flag) {
  if (threadIdx.x == 0 && blockIdx.x == 0) {
    int all0 = 1;
    for (int i = 0; i < 128; ++i) {
      if (ei[2 * i + 1] != 0) { all0 = 0; break; }
    }
    flag[0] = all0;  // 1 => int64 payload (high words all zero)
  }
}

__global__ void init_kernel(int* __restrict__ cnt, float* __restrict__ pooled, int N) {
  int i = blockIdx.x * 256 + threadIdx.x;
  if (i < N) cnt[i] = 0;
  if (i < 512) pooled[i] = 0.f;  // sum[0:256]=0, max bits[256:512]=+0.0 (h>=0)
}

__global__ void count_kernel(const int* __restrict__ ei, const int* __restrict__ flag,
                             int* __restrict__ cnt, int E) {
  int e = blockIdx.x * 256 + threadIdx.x;
  if (e >= E) return;
  int d;
  if (flag[0]) d = (int)((const long long*)ei)[(size_t)E + e];
  else         d = ei[(size_t)E + e];
  atomicAdd(&cnt[d], 1);
}

// 3-phase multiblock exclusive scan over cnt[N] -> rowptr[N+1] (+cursor, bucket cursors), dinv.

__global__ __launch_bounds__(256) void bsum_kernel(const int* __restrict__ cnt,
                                                   int* __restrict__ bsum, int N) {
  __shared__ int red[4];
  int t = threadIdx.x;
  int i = blockIdx.x * 256 + t;
  int v = (i < N) ? cnt[i] : 0;
  for (int off = 32; off > 0; off >>= 1) v += __shfl_down(v, off, 64);
  if ((t & 63) == 0) red[t >> 6] = v;
  __syncthreads();
  if (t == 0) bsum[blockIdx.x] = red[0] + red[1] + red[2] + red[3];
}

__global__ __launch_bounds__(256) void bscan_kernel(const int* __restrict__ bsum,
                                                    int* __restrict__ boff,
                                                    int* __restrict__ rowptr, int B, int N) {
  __shared__ int s[256];
  int t = threadIdx.x;
  int v = (t < B) ? bsum[t] : 0;
  s[t] = v;
  __syncthreads();
  for (int off = 1; off < 256; off <<= 1) {
    int x = s[t];
    int add = (t >= off) ? s[t - off] : 0;
    __syncthreads();
    s[t] = x + add;
    __syncthreads();
  }
  if (t < B) boff[t] = s[t] - v;  // exclusive block offset
  if (t == 255) rowptr[N] = s[255];
}

// bcursor is line-padded: bucket b's cursor lives at bcursor[b*16] (64 B apart).
__global__ __launch_bounds__(256) void rowptr_kernel(const int* __restrict__ cnt,
                                                     const int* __restrict__ boff,
                                                     int* __restrict__ rowptr,
                                                     int* __restrict__ cursor,
                                                     int* __restrict__ bcursor,
                                                     float* __restrict__ dinv, int N) {
  __shared__ int s[256];
  int t = threadIdx.x;
  int i = blockIdx.x * 256 + t;
  int v = (i < N) ? cnt[i] : 0;
  s[t] = v;
  __syncthreads();
  for (int off = 1; off < 256; off <<= 1) {
    int x = s[t];
    int add = (t >= off) ? s[t - off] : 0;
    __syncthreads();
    s[t] = x + add;
    __syncthreads();
  }
  if (i < N) {
    int rp = boff[blockIdx.x] + s[t] - v;
    rowptr[i] = rp;
    cursor[i] = rp;                       // per-node cursor for phase-2 scatter
    if ((i & 63) == 0) bcursor[(i >> 6) * 16] = rp;  // per-bucket cursor for binning
    dinv[i] = rsqrtf((float)(v + 1));     // +1 self-loop
  }
}

// Phase 1: bin edges by dst-bucket (dst>>6). Bucket regions in pair-space are
// exactly the rowptr slices, so appends are quasi-sequential per bucket.
__global__ void bin_kernel(const int* __restrict__ ei, const int* __restrict__ flag,
                           int* __restrict__ bcursor, unsigned* __restrict__ pairs, int E) {
  int e = blockIdx.x * 256 + threadIdx.x;
  if (e >= E) return;
  int s, d;
  if (flag[0]) {
    const long long* e64 = (const long long*)ei;
    s = (int)e64[e];
    d = (int)e64[(size_t)E + e];
  } else {
    s = ei[e];
    d = ei[(size_t)E + e];
  }
  int pos = atomicAdd(&bcursor[(d >> 6) * 16], 1);
  pairs[pos] = (unsigned)s | ((unsigned)d << 16);  // s,d < 65536
}

// Phase 2: one block per bucket; reads its pair range coalesced, scatters src ids
// into the bucket's ~contiguous col region (L2-resident, no line thrash).
__global__ __launch_bounds__(256) void scatter2_kernel(const unsigned* __restrict__ pairs,
                                                       const int* __restrict__ rowptr,
                                                       int* __restrict__ cursor,
                                                       ushort* __restrict__ col, int N, int E) {
  int b = blockIdx.x;
  int beg = rowptr[b * 64];
  int endn = min(b * 64 + 64, N);
  int end = rowptr[endn];
  for (int j = beg + threadIdx.x; j < end; j += 256) {
    unsigned p = pairs[j];
    int s = p & 0xffff;
    int d = p >> 16;
    int pos = atomicAdd(&cursor[d], 1);
    col[pos] = (ushort)s;
  }
}

// -------------------- bf16 conversion / weight packing --------------------

__global__ void cvt_x_kernel(const float* __restrict__ x, ushort* __restrict__ xb,
                             int n, int npad) {
  int i = blockIdx.x * 256 + threadIdx.x;
  if (i < n) xb[i] = f2bf(x[i]);
  else if (i < npad) xb[i] = 0;
}

// Wp layout: [K/32][16 colblk][64 lane][8 bf16], element (ks,cb,lane,i):
//   k = ks*32 + (lane>>4)*8 + i,  n = cb*16 + (lane&15)   (MFMA B-frag order)
__global__ void pack_w_kernel(const float* __restrict__ W, ushort* __restrict__ Wp, int K) {
  int idx = blockIdx.x * 256 + threadIdx.x;
  int total = (K >> 5) * 16 * 64;
  if (idx >= total) return;
  int lane = idx & 63;
  int cb = (idx >> 6) & 15;
  int ks = idx >> 10;
  int n = cb * 16 + (lane & 15);
  int kbase = ks * 32 + (lane >> 4) * 8;
#pragma unroll
  for (int i = 0; i < 8; ++i)
    Wp[(size_t)idx * 8 + i] = f2bf(W[(size_t)(kbase + i) * 256 + n]);
}

// -------------------- bf16 MFMA GEMM: C[M,256] = post(A[M,K] @ W) --------------------
// block = 256 thr (4 waves), tile 64 rows x 256 cols; wave w owns cols w*64..+63.
// Per wave: 4 rowblk x 4 colblk 16x16 frags, K-loop step 32.
// Output: bf16 to C, or (if C8) fp8 e4m3 of value*FP8_SCALE (post bias/relu/scale).

__global__ __launch_bounds__(256) void gemm_mfma_kernel(
    const ushort* __restrict__ A,   // [Mpad,K] bf16 row-major
    const ushort* __restrict__ Wp,  // packed frags
    const float* __restrict__ bias, // [256] or null
    const float* __restrict__ scale,// [M] dinv or null (applied after bias/relu)
    ushort* __restrict__ C,         // [Mpad,256] bf16 (if C8 == null)
    unsigned char* __restrict__ C8, // [Mpad,256] fp8 (or null)
    int M, int K, int relu) {
  int t = threadIdx.x;
  int lane = t & 63, wave = t >> 6;
  int l15 = lane & 15, lk = lane >> 4;
  int row0 = blockIdx.x * 64;

  f32x4 acc[4][4];
#pragma unroll
  for (int rb = 0; rb < 4; ++rb)
#pragma unroll
    for (int cb = 0; cb < 4; ++cb) acc[rb][cb] = (f32x4){0.f, 0.f, 0.f, 0.f};

  const ushort* abase[4];
#pragma unroll
  for (int rb = 0; rb < 4; ++rb)
    abase[rb] = A + (size_t)(row0 + rb * 16 + l15) * K + lk * 8;
  const ushort* bbase = Wp + ((size_t)(wave * 4) * 64 + lane) * 8;

  int nks = K >> 5;
  for (int ks = 0; ks < nks; ++ks) {
    bf16x8 a[4], b[4];
#pragma unroll
    for (int rb = 0; rb < 4; ++rb)
      a[rb] = *reinterpret_cast<const bf16x8*>(abase[rb] + ks * 32);
#pragma unroll
    for (int cb = 0; cb < 4; ++cb)
      b[cb] = *reinterpret_cast<const bf16x8*>(bbase + ((size_t)ks * 16 + cb) * 64 * 8);
#pragma unroll
    for (int rb = 0; rb < 4; ++rb)
#pragma unroll
      for (int cb = 0; cb < 4; ++cb)
        acc[rb][cb] = __builtin_amdgcn_mfma_f32_16x16x32_bf16(a[rb], b[cb], acc[rb][cb], 0, 0, 0);
  }

  float bv[4];
#pragma unroll
  for (int cb = 0; cb < 4; ++cb)
    bv[cb] = bias ? bias[wave * 64 + cb * 16 + l15] : 0.f;

#pragma unroll
  for (int rb = 0; rb < 4; ++rb) {
    int rbase = row0 + rb * 16 + lk * 4;
#pragma unroll
    for (int r = 0; r < 4; ++r) {
      int row = rbase + r;
      if (row >= M) continue;
      float sc = scale ? scale[row] : 1.f;
#pragma unroll
      for (int cb = 0; cb < 4; ++cb) {
        float v = acc[rb][cb][r] + bv[cb];
        if (relu) v = fmaxf(v, 0.f);
        v *= sc;
        int colIdx = wave * 64 + cb * 16 + l15;
        if (C8) {
          float vq = fminf(fmaxf(v * FP8_SCALE, -448.f), 448.f);
          unsigned p = __builtin_amdgcn_cvt_pk_fp8_f32(vq, vq, 0, false);
          C8[(size_t)row * 256 + colIdx] = (unsigned char)(p & 0xff);
        } else {
          C[(size_t)row * 256 + colIdx] = f2bf(v);
        }
      }
    }
  }
}

// -------- message passing: h[n] = relu(dinv[n]*(sum_{s in in(n)} hw'[s] + hw'[n]) + b) ----
// hw' rows are fp8 e4m3 of (hw * dinv[src] * FP8_SCALE); dn folds dinv[n]/FP8_SCALE.
// Edge loop unrolled x4 with independent loads to raise memory-level parallelism.

__global__ __launch_bounds__(64) void mp_kernel(const unsigned char* __restrict__ hw8,
                                                const int* __restrict__ rowptr,
                                                const ushort* __restrict__ col,
                                                const float* __restrict__ dinv,
                                                const float* __restrict__ bias,
                                                ushort* __restrict__ hout) {
  int n = blockIdx.x;
  int t = threadIdx.x;  // 64 lanes x 4 fp8 = 256 cols
  const unsigned* hw32 = reinterpret_cast<const unsigned*>(hw8);
  unsigned ws = hw32[(size_t)n * 64 + t];  // self
  f32x2 lo = __builtin_amdgcn_cvt_pk_f32_fp8(ws, false);
  f32x2 hi = __builtin_amdgcn_cvt_pk_f32_fp8(ws, true);
  float ax = lo[0], ay = lo[1], az = hi[0], aw = hi[1];
  int beg = rowptr[n], end = rowptr[n + 1];
  int j = beg;
  for (; j + 4 <= end; j += 4) {
    int s0 = col[j], s1 = col[j + 1], s2 = col[j + 2], s3 = col[j + 3];
    unsigned w0 = hw32[(size_t)s0 * 64 + t];
    unsigned w1 = hw32[(size_t)s1 * 64 + t];
    unsigned w2 = hw32[(size_t)s2 * 64 + t];
    unsigned w3 = hw32[(size_t)s3 * 64 + t];
    f32x2 l0 = __builtin_amdgcn_cvt_pk_f32_fp8(w0, false);
    f32x2 h0 = __builtin_amdgcn_cvt_pk_f32_fp8(w0, true);
    f32x2 l1 = __builtin_amdgcn_cvt_pk_f32_fp8(w1, false);
    f32x2 h1 = __builtin_amdgcn_cvt_pk_f32_fp8(w1, true);
    f32x2 l2 = __builtin_amdgcn_cvt_pk_f32_fp8(w2, false);
    f32x2 h2 = __builtin_amdgcn_cvt_pk_f32_fp8(w2, true);
    f32x2 l3 = __builtin_amdgcn_cvt_pk_f32_fp8(w3, false);
    f32x2 h3 = __builtin_amdgcn_cvt_pk_f32_fp8(w3, true);
    ax += (l0[0] + l1[0]) + (l2[0] + l3[0]);
    ay += (l0[1] + l1[1]) + (l2[1] + l3[1]);
    az += (h0[0] + h1[0]) + (h2[0] + h3[0]);
    aw += (h0[1] + h1[1]) + (h2[1] + h3[1]);
  }
  for (; j < end; ++j) {
    int s = col[j];
    unsigned wv = hw32[(size_t)s * 64 + t];
    f32x2 l2 = __builtin_amdgcn_cvt_pk_f32_fp8(wv, false);
    f32x2 h2 = __builtin_amdgcn_cvt_pk_f32_fp8(wv, true);
    ax += l2[0]; ay += l2[1]; az += h2[0]; aw += h2[1];
  }
  float dn = dinv[n] * FP8_INV;
  float4 bv = *reinterpret_cast<const float4*>(bias + t * 4);
  ushort4 o;
  o.x = f2bf(fmaxf(fmaf(dn, ax, bv.x), 0.f));
  o.y = f2bf(fmaxf(fmaf(dn, ay, bv.y), 0.f));
  o.z = f2bf(fmaxf(fmaf(dn, az, bv.z), 0.f));
  o.w = f2bf(fmaxf(fmaf(dn, aw, bv.w), 0.f));
  *reinterpret_cast<ushort4*>(hout + (size_t)n * 256 + t * 4) = o;
}

// ---------- pooling: column sum+max over N rows, grid-strided 2-level reduce ----------

__global__ __launch_bounds__(256) void pool_kernel(const ushort* __restrict__ h,
                                                   float* __restrict__ pooled_sum,
                                                   unsigned* __restrict__ pooled_max, int N) {
  __shared__ float ssum[4][256];
  __shared__ float smax[4][256];
  int t = threadIdx.x;
  int w = t >> 6, l = t & 63;
  int stride = gridDim.x * 4;
  float s0 = 0.f, s1 = 0.f, s2 = 0.f, s3 = 0.f;
  float m0 = 0.f, m1 = 0.f, m2 = 0.f, m3 = 0.f;  // h >= 0 after relu
  for (int r = blockIdx.x * 4 + w; r < N; r += stride) {
    ushort4 hv = *reinterpret_cast<const ushort4*>(h + (size_t)r * 256 + l * 4);
    float v0 = bf2f(hv.x), v1 = bf2f(hv.y), v2 = bf2f(hv.z), v3 = bf2f(hv.w);
    s0 += v0; s1 += v1; s2 += v2; s3 += v3;
    m0 = fmaxf(m0, v0); m1 = fmaxf(m1, v1); m2 = fmaxf(m2, v2); m3 = fmaxf(m3, v3);
  }
  ssum[w][l * 4] = s0; ssum[w][l * 4 + 1] = s1; ssum[w][l * 4 + 2] = s2; ssum[w][l * 4 + 3] = s3;
  smax[w][l * 4] = m0; smax[w][l * 4 + 1] = m1; smax[w][l * 4 + 2] = m2; smax[w][l * 4 + 3] = m3;
  __syncthreads();
  if (w == 0) {
#pragma unroll
    for (int j = 0; j < 4; ++j) {
      int c = l * 4 + j;
      float s = ssum[0][c] + ssum[1][c] + ssum[2][c] + ssum[3][c];
      float m = fmaxf(fmaxf(smax[0][c], smax[1][c]), fmaxf(smax[2][c], smax[3][c]));
      atomicAdd(&pooled_sum[c], s);
      atomicMax(&pooled_max[c], __float_as_uint(m));  // valid: non-negative floats
    }
  }
}

// -------------------- head: graph projection + decoder + scalar logit (f32) ------------

__global__ __launch_bounds__(256) void head_kernel(const float* __restrict__ pooled,
                                                   const float* __restrict__ Wg1, const float* __restrict__ bg1,
                                                   const float* __restrict__ Wg2, const float* __restrict__ bg2,
                                                   const float* __restrict__ Wd1, const float* __restrict__ bd1,
                                                   const float* __restrict__ Wd2, const float* __restrict__ bd2,
                                                   float* __restrict__ out_ge, float* __restrict__ s_out, int N) {
  __shared__ float gr[512];
  __shared__ float t1[256];
  __shared__ float ge[128];
  __shared__ float t2[256];
  __shared__ float v[256];
  __shared__ float red[4];
  int t = threadIdx.x;
  gr[t] = pooled[t] / (float)N;                                       // mean
  gr[256 + t] = __uint_as_float(((const unsigned*)pooled)[256 + t]);  // max (bit-stored)
  __syncthreads();
  float acc = bg1[t];
  for (int k = 0; k < 512; ++k) acc = fmaf(gr[k], Wg1[k * 256 + t], acc);
  t1[t] = fmaxf(acc, 0.f);
  __syncthreads();
  if (t < 128) {
    float a = bg2[t];
    for (int k = 0; k < 256; ++k) a = fmaf(t1[k], Wg2[k * 128 + t], a);
    ge[t] = a;
    out_ge[t] = a;  // output 0: graph_embedding
  }
  __syncthreads();
  acc = bd1[t];
  for (int k = 0; k < 128; ++k) acc = fmaf(ge[k], Wd1[k * 256 + t], acc);
  t2[t] = fmaxf(acc, 0.f);
  __syncthreads();
  acc = bd2[t];
  for (int k = 0; k < 256; ++k) acc = fmaf(t2[k], Wd2[k * 256 + t], acc);
  v[t] = acc;
  __syncthreads();
  float p = v[t] * v[t];
  for (int off = 32; off > 0; off >>= 1) p += __shfl_down(p, off, 64);
  if ((t & 63) == 0) red[t >> 6] = p;
  __syncthreads();
  if (t == 0) {
    float ssq = red[0] + red[1] + red[2] + red[3];
    s_out[0] = 1.f / (1.f + expf(-ssq));
  }
}

__global__ void fill_kernel(float* __restrict__ out, const float* __restrict__ s_out, int E) {
  int i = blockIdx.x * 256 + threadIdx.x;
  if (i < E) out[i] = s_out[0];
}

// -------------------- launch --------------------

extern "C" void kernel_launch(void* const* d_in, const int* in_sizes, int n_in,
                              void* d_out, int out_size, void* d_ws, size_t ws_size,
                              hipStream_t stream) {
  const float* x   = (const float*)d_in[0];
  const int*   ei  = (const int*)d_in[1];
  const float* W1  = (const float*)d_in[2];
  const float* b1  = (const float*)d_in[3];
  const float* W2  = (const float*)d_in[4];
  const float* b2  = (const float*)d_in[5];
  const float* cW  = (const float*)d_in[6];
  const float* cb  = (const float*)d_in[7];
  const float* Wg1 = (const float*)d_in[8];
  const float* bg1 = (const float*)d_in[9];
  const float* Wg2 = (const float*)d_in[10];
  const float* bg2 = (const float*)d_in[11];
  const float* Wd1 = (const float*)d_in[12];
  const float* bd1 = (const float*)d_in[13];
  const float* Wd2 = (const float*)d_in[14];
  const float* bd2 = (const float*)d_in[15];
  float* out = (float*)d_out;

  int N = in_sizes[0] / 64;  // 50000
  int E = in_sizes[1] / 2;   // 800000
  int Mpad = (N + 63) & ~63; // 50048
  int B = (N + 255) / 256;   // scan blocks (196)
  int NB = (N + 63) / 64;    // dst buckets (782)

  size_t off = 0;
  auto walloc = [&](size_t bytes) -> void* {
    void* p = (char*)d_ws + off;
    off += (bytes + 511) & ~(size_t)511;
    return p;
  };
  ushort* hA    = (ushort*)walloc((size_t)Mpad * 256 * 2);
  ushort* hB    = (ushort*)walloc((size_t)Mpad * 256 * 2);
  unsigned char* hA8 = (unsigned char*)walloc((size_t)Mpad * 256);
  ushort* xb    = (ushort*)walloc((size_t)Mpad * 64 * 2);
  ushort* Wp1   = (ushort*)walloc((size_t)2 * 16 * 64 * 8 * 2);
  ushort* Wp2   = (ushort*)walloc((size_t)8 * 16 * 64 * 8 * 2);
  ushort* Wpc   = (ushort*)walloc((size_t)3 * 8 * 16 * 64 * 8 * 2);
  int*   cnt    = (int*)walloc((size_t)N * 4);
  int*   rowptr = (int*)walloc(((size_t)N + 1) * 4);
  int*   cursor = (int*)walloc((size_t)N * 4);
  int*   bcursor= (int*)walloc((size_t)NB * 16 * 4);  // line-padded
  float* dinv   = (float*)walloc((size_t)N * 4);
  unsigned* pairs = (unsigned*)walloc((size_t)E * 4);
  ushort* col   = (ushort*)walloc((size_t)E * 2);
  int*   bsum   = (int*)walloc(256 * 4);
  int*   boff   = (int*)walloc(256 * 4);
  float* pooled = (float*)walloc(512 * 4);
  float* s_out  = (float*)walloc(512);
  int*   flag   = (int*)walloc(512);

  // graph structure (CSR by dst, ushort col)
  detect_i64_kernel<<<1, 64, 0, stream>>>(ei, flag);
  init_kernel<<<(N + 255) / 256, 256, 0, stream>>>(cnt, pooled, N);
  count_kernel<<<(E + 255) / 256, 256, 0, stream>>>(ei, flag, cnt, E);
  bsum_kernel<<<B, 256, 0, stream>>>(cnt, bsum, N);
  bscan_kernel<<<1, 256, 0, stream>>>(bsum, boff, rowptr, B, N);
  rowptr_kernel<<<B, 256, 0, stream>>>(cnt, boff, rowptr, cursor, bcursor, dinv, N);
  bin_kernel<<<(E + 255) / 256, 256, 0, stream>>>(ei, flag, bcursor, pairs, E);
  scatter2_kernel<<<NB, 256, 0, stream>>>(pairs, rowptr, cursor, col, N, E);

  // bf16 conversion + weight packing
  cvt_x_kernel<<<(Mpad * 64 + 255) / 256, 256, 0, stream>>>(x, xb, N * 64, Mpad * 64);
  pack_w_kernel<<<(2 * 16 * 64 + 255) / 256, 256, 0, stream>>>(W1, Wp1, 64);
  pack_w_kernel<<<(8 * 16 * 64 + 255) / 256, 256, 0, stream>>>(W2, Wp2, 256);
  for (int l = 0; l < 3; ++l)
    pack_w_kernel<<<(8 * 16 * 64 + 255) / 256, 256, 0, stream>>>(
        cW + (size_t)l * 256 * 256, Wpc + (size_t)l * 8 * 16 * 64 * 8, 256);

  int gblocks = Mpad / 64;
  // encoder (bf16 out)
  gemm_mfma_kernel<<<gblocks, 256, 0, stream>>>(xb, Wp1, b1, nullptr, hA, nullptr, N, 64, 1);
  gemm_mfma_kernel<<<gblocks, 256, 0, stream>>>(hA, Wp2, b2, nullptr, hB, nullptr, N, 256, 0);
  // GCN layers: hw' = (h @ convW) * dinv[row] -> fp8(x32); h = relu(dinv*(gather+self) + b)
  for (int l = 0; l < 3; ++l) {
    gemm_mfma_kernel<<<gblocks, 256, 0, stream>>>(
        hB, Wpc + (size_t)l * 8 * 16 * 64 * 8, nullptr, dinv, nullptr, hA8, N, 256, 0);
    mp_kernel<<<N, 64, 0, stream>>>(hA8, rowptr, col, dinv, cb + (size_t)l * 256, hB);
  }
  // readout
  pool_kernel<<<392, 256, 0, stream>>>(hB, pooled, (unsigned*)(pooled + 256), N);
  head_kernel<<<1, 256, 0, stream>>>(pooled, Wg1, bg1, Wg2, bg2, Wd1, bd1, Wd2, bd2, out, s_out, N);
  fill_kernel<<<(E + 255) / 256, 256, 0, stream>>>(out + 128, s_out, E);
}